// Round 2
// baseline (175.472 us; speedup 1.0000x reference)
//
#include <hip/hip_runtime.h>
#include <hip/hip_bf16.h>
#include <stdint.h>

// Problem constants
#define B_   4
#define P_   20000
#define NB_  9
#define WN_  17
#define CI_  64
#define CO_  128
#define PTS  16           // points per block
#define ROWS 64           // 4 batches * 16 points = GEMM rows per block

typedef short bf16x8  __attribute__((ext_vector_type(8)));
typedef float f32x16  __attribute__((ext_vector_type(16)));

union U128 { uint4 u; ushort s[8]; };

__device__ __forceinline__ ushort f2bf(float f) {
    union { float f; uint32_t u; } c; c.f = f;
    uint32_t u = c.u;
    uint32_t r = u + 0x7fff + ((u >> 16) & 1);   // RTNE
    return (ushort)(r >> 16);
}

__global__ __launch_bounds__(256, 2)
void lasm_fused(const float* __restrict__ in_pc,    // (B,P,CI)    f32
                const float* __restrict__ raw_w,    // (P,NB,WN)   f32
                const float* __restrict__ weights,  // (WN,CO*CI)  f32
                const float* __restrict__ bias,     // (P,CO)      f32
                const int*   __restrict__ nbr,      // (P,NB)      int32
                float*       __restrict__ out)      // (B,P,CO)    f32
{
    __shared__ __align__(16) int    s_nid[PTS][NB_];
    __shared__ __align__(16) float  s_w[PTS][WN_][12];  // [pl][m][n], n padded 9->12
    __shared__ __align__(16) ushort s_a[ROWS * 64];     // fuse chunk (bf16), XOR-oct swizzled
    __shared__ __align__(16) ushort s_b[CO_ * 64];      // Wm chunk (bf16), co-major, swizzled

    const int tid  = threadIdx.x;
    const int lane = tid & 63;
    const int wv   = tid >> 6;
    const int p0   = blockIdx.x * PTS;

    // ---- neighbor ids ----
    if (tid < PTS * NB_) {
        int pl = tid / NB_, n = tid % NB_;
        s_nid[pl][n] = nbr[(p0 + pl) * NB_ + n];
    }
    // ---- w transpose [p][n][m] -> [pl][m][n], fp32 (mask folded into x) ----
    for (int idx = tid; idx < PTS * NB_ * WN_; idx += 256) {
        int pl = idx / (NB_ * WN_);
        int r  = idx % (NB_ * WN_);
        int n  = r / WN_;
        int m  = r % WN_;
        s_w[pl][m][n] = raw_w[(size_t)(p0 + pl) * NB_ * WN_ + n * WN_ + m];
    }
    for (int idx = tid; idx < PTS * WN_; idx += 256) {
        int pl = idx / WN_, m = idx % WN_;
        s_w[pl][m][9] = 0.f; s_w[pl][m][10] = 0.f; s_w[pl][m][11] = 0.f;
    }
    __syncthreads();

    // ---- per-thread x gather into registers (fp32) ----
    // thread t: i-oct = t&7 (channels oct*8..oct*8+7), row pair {rp, rp+32}, rp = t>>3
    const int oct = tid & 7;
    const int rp  = tid >> 3;            // 0..31
    float x[2][NB_][8];
    #pragma unroll
    for (int rr = 0; rr < 2; ++rr) {
        int r  = rp + rr * 32;           // GEMM row = b*16 + pl
        int b  = r >> 4;
        int pl = r & 15;
        #pragma unroll
        for (int n = 0; n < NB_; ++n) {
            int nid = s_nid[pl][n];
            if (nid < P_) {
                const float* src = in_pc + ((size_t)(b * P_ + nid)) * CI_ + oct * 8;
                float4 v0 = *(const float4*)(src);
                float4 v1 = *(const float4*)(src + 4);
                x[rr][n][0] = v0.x; x[rr][n][1] = v0.y; x[rr][n][2] = v0.z; x[rr][n][3] = v0.w;
                x[rr][n][4] = v1.x; x[rr][n][5] = v1.y; x[rr][n][6] = v1.z; x[rr][n][7] = v1.w;
            } else {
                #pragma unroll
                for (int j = 0; j < 8; ++j) x[rr][n][j] = 0.f;
            }
        }
    }

    f32x16 acc0, acc1;
    #pragma unroll
    for (int j = 0; j < 16; ++j) { acc0[j] = 0.f; acc1[j] = 0.f; }

    const int co_base = wv * 32;
    const int arow    = lane & 31;
    const int q       = lane >> 5;

    for (int m = 0; m < WN_; ++m) {
        // ---- stage Wm chunk -> s_b (bf16, co-major, swizzled). coalesced ----
        #pragma unroll
        for (int j = 0; j < 4; ++j) {
            int flat = j * 256 + tid;                 // 0..1023
            int co = flat >> 3, o = flat & 7;
            const float* src = weights + (size_t)m * (CO_ * CI_) + co * CI_ + o * 8;
            float4 v0 = *(const float4*)(src);
            float4 v1 = *(const float4*)(src + 4);
            U128 v;
            v.s[0] = f2bf(v0.x); v.s[1] = f2bf(v0.y); v.s[2] = f2bf(v0.z); v.s[3] = f2bf(v0.w);
            v.s[4] = f2bf(v1.x); v.s[5] = f2bf(v1.y); v.s[6] = f2bf(v1.z); v.s[7] = f2bf(v1.w);
            int op = o ^ (co & 7);
            *(uint4*)&s_b[co * 64 + op * 8] = v.u;
        }
        // ---- stage-1: fuse slice for this m -> s_a (fp32 math, bf16 store) ----
        {
            int pl = rp & 15;                          // same pl for both rows
            const float* wrow = &s_w[pl][m][0];
            float4 w0 = *(const float4*)(wrow);
            float4 w1 = *(const float4*)(wrow + 4);
            float  w8 = wrow[8];
            #pragma unroll
            for (int rr = 0; rr < 2; ++rr) {
                int r = rp + rr * 32;
                float c[8];
                #pragma unroll
                for (int j = 0; j < 8; ++j) {
                    c[j] = w0.x * x[rr][0][j] + w0.y * x[rr][1][j]
                         + w0.z * x[rr][2][j] + w0.w * x[rr][3][j]
                         + w1.x * x[rr][4][j] + w1.y * x[rr][5][j]
                         + w1.z * x[rr][6][j] + w1.w * x[rr][7][j]
                         + w8   * x[rr][8][j];
                }
                U128 v;
                #pragma unroll
                for (int j = 0; j < 8; ++j) v.s[j] = f2bf(c[j]);
                int op = oct ^ (r & 7);
                *(uint4*)&s_a[r * 64 + op * 8] = v.u;
            }
        }
        __syncthreads();
        // ---- MFMA: K=64 chunk as 4 x k16; wave owns co-tile wv, both M-tiles ----
        #pragma unroll
        for (int ks = 0; ks < 4; ++ks) {
            int o = ks * 2 + q;                        // i-oct index
            int bco = co_base + arow;
            bf16x8 bf = *(const bf16x8*)&s_b[bco * 64 + (o ^ (bco & 7)) * 8];
            bf16x8 a0 = *(const bf16x8*)&s_a[arow * 64 + (o ^ (arow & 7)) * 8];
            bf16x8 a1 = *(const bf16x8*)&s_a[(arow + 32) * 64 + (o ^ (arow & 7)) * 8];
            acc0 = __builtin_amdgcn_mfma_f32_32x32x16_bf16(a0, bf, acc0, 0, 0, 0);
            acc1 = __builtin_amdgcn_mfma_f32_32x32x16_bf16(a1, bf, acc1, 0, 0, 0);
        }
        __syncthreads();
    }

    // ---- epilogue: bias + ELU + fp32 store ----
    const int col   = co_base + (lane & 31);
    const int rbase = 4 * (lane >> 5);
    #pragma unroll
    for (int mt = 0; mt < 2; ++mt) {
        f32x16 acc = mt ? acc1 : acc0;
        #pragma unroll
        for (int v = 0; v < 16; ++v) {
            int row = mt * 32 + (v & 3) + 8 * (v >> 2) + rbase;
            int b   = row >> 4;
            int p   = p0 + (row & 15);
            float val = acc[v] + bias[(size_t)p * CO_ + col];
            val = (val > 0.f) ? val : (__expf(val) - 1.f);
            out[((size_t)b * P_ + p) * CO_ + col] = val;
        }
    }
}

extern "C" void kernel_launch(void* const* d_in, const int* in_sizes, int n_in,
                              void* d_out, int out_size, void* d_ws, size_t ws_size,
                              hipStream_t stream) {
    const float* in_pc   = (const float*)d_in[0];
    const float* raw_w   = (const float*)d_in[1];
    const float* weights = (const float*)d_in[2];
    const float* bias    = (const float*)d_in[3];
    const int*   nbr     = (const int*)  d_in[4];
    float* out = (float*)d_out;

    lasm_fused<<<dim3(P_ / PTS), dim3(256), 0, stream>>>(
        in_pc, raw_w, weights, bias, nbr, out);
}

// Round 4
// 169.570 us; speedup vs baseline: 1.0348x; 1.0348x over previous
//
#include <hip/hip_runtime.h>
#include <hip/hip_bf16.h>
#include <stdint.h>

// Problem constants
#define B_   4
#define P_   20000
#define NB_  9
#define WN_  17
#define CI_  64
#define CO_  128
#define PTS  16           // points per block
#define ROWS 64           // 4 batches * 16 points = GEMM rows per block

typedef __fp16 f16x8 __attribute__((ext_vector_type(8)));
typedef __fp16 h2    __attribute__((ext_vector_type(2)));
typedef float  f32x16 __attribute__((ext_vector_type(16)));

union H2U { h2 h; uint32_t u; };
union H8U { __fp16 h[8]; uint4 u; };

// ---- prep kernel: Wm fp32 -> f16, pre-swizzled into LDS layout ----
// wsb[m*8192 + co*64 + (o^(co&7))*8 + j]  (ushort elements)
__global__ void prep_wm(const float* __restrict__ w, ushort* __restrict__ wsb) {
    int i = blockIdx.x * 256 + threadIdx.x;      // granule = 8 elems; 17*128*8 total
    int m  = i >> 10;                            // / 1024
    int r  = i & 1023;
    int co = r >> 3;
    int o  = r & 7;
    const float* src = w + (size_t)m * (CO_ * CI_) + co * CI_ + o * 8;
    float4 v0 = *(const float4*)(src);
    float4 v1 = *(const float4*)(src + 4);
    H8U h;
    *(h2*)&h.h[0] = __builtin_amdgcn_cvt_pkrtz(v0.x, v0.y);
    *(h2*)&h.h[2] = __builtin_amdgcn_cvt_pkrtz(v0.z, v0.w);
    *(h2*)&h.h[4] = __builtin_amdgcn_cvt_pkrtz(v1.x, v1.y);
    *(h2*)&h.h[6] = __builtin_amdgcn_cvt_pkrtz(v1.z, v1.w);
    *(uint4*)&wsb[m * 8192 + co * 64 + (o ^ (co & 7)) * 8] = h.u;
}

template <bool PRE>
__global__ __launch_bounds__(256, 2)
void lasm_fused(const float* __restrict__ in_pc,    // (B,P,CI)    f32
                const float* __restrict__ raw_w,    // (P,NB,WN)   f32
                const float* __restrict__ weights,  // (WN,CO*CI)  f32
                const float* __restrict__ bias,     // (P,CO)      f32
                const int*   __restrict__ nbr,      // (P,NB)      int32
                const ushort* __restrict__ wsb,     // (WN,CO,CI)  f16 pre-swizzled
                float*       __restrict__ out)      // (B,P,CO)    f32
{
    __shared__ __align__(16) int      s_nid[PTS][NB_];
    __shared__ __align__(16) uint32_t s_w2[PTS][WN_][12];  // f16x2 splat, n padded ->12
    __shared__ __align__(16) ushort   s_a[2][ROWS * 64];   // fuse (f16), XOR-oct swizzled
    __shared__ __align__(16) ushort   s_b[2][CO_ * 64];    // Wm (f16), co-major, swizzled

    const int tid  = threadIdx.x;
    const int lane = tid & 63;
    const int wv   = tid >> 6;
    const int p0   = blockIdx.x * PTS;

    // ---- neighbor ids ----
    if (tid < PTS * NB_) {
        int pl = tid / NB_, n = tid % NB_;
        s_nid[pl][n] = nbr[(p0 + pl) * NB_ + n];
    }
    // ---- w: [p][n][m] -> [pl][m][n] as f16x2 splat (mask folded into x) ----
    for (int idx = tid; idx < PTS * NB_ * WN_; idx += 256) {
        int pl = idx / (NB_ * WN_);
        int r  = idx % (NB_ * WN_);
        int n  = r / WN_;
        int m  = r % WN_;
        float wf = raw_w[(size_t)(p0 + pl) * NB_ * WN_ + n * WN_ + m];
        H2U c; c.h = __builtin_amdgcn_cvt_pkrtz(wf, wf);
        s_w2[pl][m][n] = c.u;
    }
    for (int idx = tid; idx < PTS * WN_; idx += 256) {
        int pl = idx / WN_, m = idx % WN_;
        s_w2[pl][m][9] = 0u; s_w2[pl][m][10] = 0u; s_w2[pl][m][11] = 0u;
    }
    __syncthreads();

    // ---- per-thread x gather -> f16 pairs in registers ----
    // thread t: i-oct = t&7 (ch oct*8..+7), row pair {rp, rp+32}, rp = t>>3
    const int oct = tid & 7;
    const int rp  = tid >> 3;            // 0..31
    h2 x[2][NB_][4];
    #pragma unroll
    for (int rr = 0; rr < 2; ++rr) {
        int r  = rp + rr * 32;           // GEMM row = b*16 + pl
        int b  = r >> 4;
        int pl = r & 15;
        #pragma unroll
        for (int n = 0; n < NB_; ++n) {
            int nid = s_nid[pl][n];
            if (nid < P_) {
                const float* src = in_pc + ((size_t)(b * P_ + nid)) * CI_ + oct * 8;
                float4 v0 = *(const float4*)(src);
                float4 v1 = *(const float4*)(src + 4);
                x[rr][n][0] = __builtin_amdgcn_cvt_pkrtz(v0.x, v0.y);
                x[rr][n][1] = __builtin_amdgcn_cvt_pkrtz(v0.z, v0.w);
                x[rr][n][2] = __builtin_amdgcn_cvt_pkrtz(v1.x, v1.y);
                x[rr][n][3] = __builtin_amdgcn_cvt_pkrtz(v1.z, v1.w);
            } else {
                h2 z = {(__fp16)0.f, (__fp16)0.f};
                x[rr][n][0] = z; x[rr][n][1] = z; x[rr][n][2] = z; x[rr][n][3] = z;
            }
        }
    }

    f32x16 acc0, acc1;
    #pragma unroll
    for (int j = 0; j < 16; ++j) { acc0[j] = 0.f; acc1[j] = 0.f; }

    const int co_base = wv * 32;
    const int arow    = lane & 31;
    const int q       = lane >> 5;
    const int pl      = rp & 15;

    // ---- helpers as lambdas ----
    auto stage_b = [&](int m, int buf) {
        if (PRE) {
            #pragma unroll
            for (int j = 0; j < 4; ++j) {
                int flat = j * 256 + tid;                 // 16B granule index
                uint4 v = *(const uint4*)&wsb[m * 8192 + flat * 8];
                *(uint4*)&s_b[buf][flat * 8] = v;
            }
        } else {
            #pragma unroll
            for (int j = 0; j < 4; ++j) {
                int flat = j * 256 + tid;
                int co = flat >> 3, o = flat & 7;
                const float* src = weights + (size_t)m * (CO_ * CI_) + co * CI_ + o * 8;
                float4 v0 = *(const float4*)(src);
                float4 v1 = *(const float4*)(src + 4);
                H8U h;
                *(h2*)&h.h[0] = __builtin_amdgcn_cvt_pkrtz(v0.x, v0.y);
                *(h2*)&h.h[2] = __builtin_amdgcn_cvt_pkrtz(v0.z, v0.w);
                *(h2*)&h.h[4] = __builtin_amdgcn_cvt_pkrtz(v1.x, v1.y);
                *(h2*)&h.h[6] = __builtin_amdgcn_cvt_pkrtz(v1.z, v1.w);
                *(uint4*)&s_b[buf][co * 64 + (o ^ (co & 7)) * 8] = h.u;
            }
        }
    };
    auto stage_a = [&](int m, int buf) {
        const uint32_t* wrow = &s_w2[pl][m][0];
        uint4 wa = *(const uint4*)(wrow);
        uint4 wb = *(const uint4*)(wrow + 4);
        uint32_t w8u = wrow[8];
        H2U w[9];
        w[0].u = wa.x; w[1].u = wa.y; w[2].u = wa.z; w[3].u = wa.w;
        w[4].u = wb.x; w[5].u = wb.y; w[6].u = wb.z; w[7].u = wb.w;
        w[8].u = w8u;
        #pragma unroll
        for (int rr = 0; rr < 2; ++rr) {
            int r = rp + rr * 32;
            h2 c0 = {(__fp16)0.f, (__fp16)0.f}, c1 = c0, c2 = c0, c3 = c0;
            #pragma unroll
            for (int n = 0; n < NB_; ++n) {
                h2 wn = w[n].h;
                c0 += wn * x[rr][n][0];
                c1 += wn * x[rr][n][1];
                c2 += wn * x[rr][n][2];
                c3 += wn * x[rr][n][3];
            }
            H8U v;
            *(h2*)&v.h[0] = c0; *(h2*)&v.h[2] = c1;
            *(h2*)&v.h[4] = c2; *(h2*)&v.h[6] = c3;
            *(uint4*)&s_a[buf][r * 64 + (oct ^ (r & 7)) * 8] = v.u;
        }
    };

    // ---- prologue: prep m=0 ----
    stage_b(0, 0);
    stage_a(0, 0);
    __syncthreads();

    int cur = 0;
    for (int m = 0; m < WN_; ++m) {
        int nxt = cur ^ 1;
        if (m + 1 < WN_) {
            stage_b(m + 1, nxt);       // global loads issued early
            stage_a(m + 1, nxt);       // VALU while MFMA pipe busy (cross-wave)
        }
        // ---- MFMA on cur: K=64 chunk as 4 x k16 ----
        #pragma unroll
        for (int ks = 0; ks < 4; ++ks) {
            int o = ks * 2 + q;
            int bco = co_base + arow;
            f16x8 bf = *(const f16x8*)&s_b[cur][bco * 64 + (o ^ (bco & 7)) * 8];
            f16x8 a0 = *(const f16x8*)&s_a[cur][arow * 64 + (o ^ (arow & 7)) * 8];
            f16x8 a1 = *(const f16x8*)&s_a[cur][(arow + 32) * 64 + (o ^ (arow & 7)) * 8];
            acc0 = __builtin_amdgcn_mfma_f32_32x32x16_f16(a0, bf, acc0, 0, 0, 0);
            acc1 = __builtin_amdgcn_mfma_f32_32x32x16_f16(a1, bf, acc1, 0, 0, 0);
        }
        __syncthreads();
        cur = nxt;
    }

    // ---- epilogue: bias + ELU + fp32 store ----
    const int col   = co_base + (lane & 31);
    const int rbase = 4 * (lane >> 5);
    #pragma unroll
    for (int mt = 0; mt < 2; ++mt) {
        f32x16 acc = mt ? acc1 : acc0;
        #pragma unroll
        for (int v = 0; v < 16; ++v) {
            int row = mt * 32 + (v & 3) + 8 * (v >> 2) + rbase;
            int b   = row >> 4;
            int p   = p0 + (row & 15);
            float val = acc[v] + bias[(size_t)p * CO_ + col];
            val = (val > 0.f) ? val : (__expf(val) - 1.f);
            out[((size_t)b * P_ + p) * CO_ + col] = val;
        }
    }
}

extern "C" void kernel_launch(void* const* d_in, const int* in_sizes, int n_in,
                              void* d_out, int out_size, void* d_ws, size_t ws_size,
                              hipStream_t stream) {
    const float* in_pc   = (const float*)d_in[0];
    const float* raw_w   = (const float*)d_in[1];
    const float* weights = (const float*)d_in[2];
    const float* bias    = (const float*)d_in[3];
    const int*   nbr     = (const int*)  d_in[4];
    float* out = (float*)d_out;

    const size_t need = (size_t)WN_ * CO_ * CI_ * sizeof(ushort);   // 278,528 B
    if (d_ws != nullptr && ws_size >= need) {
        ushort* wsb = (ushort*)d_ws;
        prep_wm<<<dim3((WN_ * CO_ * 8) / 256), dim3(256), 0, stream>>>(weights, wsb);
        lasm_fused<true><<<dim3(P_ / PTS), dim3(256), 0, stream>>>(
            in_pc, raw_w, weights, bias, nbr, wsb, out);
    } else {
        lasm_fused<false><<<dim3(P_ / PTS), dim3(256), 0, stream>>>(
            in_pc, raw_w, weights, bias, nbr, nullptr, out);
    }
}